// Round 12
// baseline (158.983 us; speedup 1.0000x reference)
//
#include <hip/hip_runtime.h>

#define E_EDGES 131072
// Layer dims: in {2048,4096,4096} -> out {4096,4096,1024}, batch 1024.
// Activations feature-major (hT[feat][1024]); CSR-by-dst built on device with
// no global atomics (LDS histogram -> scan -> LDS-cursor scatter).
// Rows padded to multiples of 8 (zero pads written inline by scan_kernel).
// SpMM v3 (dual-stream): each wave owns TWO rows (A=r0, B=r0+1, contiguous in
// CSR) with independent accumulators; per loop iteration it issues 8 float4
// gathers for A and 8 for B (16 KB in flight/wave) so one stream's dependency
// drain overlaps the other's issue. Flush is a branch-free epilogue (one row
// per stream). Edge metadata scalar via readfirstlane'd wave id.

#define EPAD01 163840   // capacity, layers 0,1 (4096 rows, E + 8*rows)
#define EPAD2  139264   // capacity, layer 2  (1024 rows)
#define C_CH   16       // chunks per layer (preprocessing)
#define CHUNK  (E_EDGES / C_CH)   // 8192 edges per chunk

typedef int iv4 __attribute__((ext_vector_type(4)));

// K1: fused transpose of x (blocks 0..2047) + dst histogram (blocks 2048..2095).
__global__ void __launch_bounds__(256) fused_tp_count_kernel(
    const float* __restrict__ x, float* __restrict__ xT,
    const int* __restrict__ d0, const int* __restrict__ d1, const int* __restrict__ d2,
    int* __restrict__ cntA) {
  __shared__ int sh[4096];
  int bid = blockIdx.x;
  int t = threadIdx.x;
  if (bid < 2048) {
    float (*tile)[33] = (float(*)[33])sh;
    int c0 = (bid & 63) << 5, r0 = (bid >> 6) << 5;
    int tx = t & 31, ty = t >> 5;  // 32 x 8
#pragma unroll
    for (int i = 0; i < 32; i += 8)
      tile[ty + i][tx] = x[(size_t)(r0 + ty + i) * 2048 + (c0 + tx)];
    __syncthreads();
#pragma unroll
    for (int i = 0; i < 32; i += 8)
      xT[(size_t)(c0 + ty + i) * 1024 + (r0 + tx)] = tile[tx][ty + i];
  } else {
    int bid2 = bid - 2048, l = bid2 >> 4, c = bid2 & 15;
    const int* dp = (l == 0) ? d0 : (l == 1) ? d1 : d2;
    for (int r = t; r < 4096; r += 256) sh[r] = 0;
    __syncthreads();
    int base = c * CHUNK;
    for (int i = 0; i < CHUNK; i += 256)
      atomicAdd(&sh[dp[base + i + t]], 1);
    __syncthreads();
    for (int r = t; r < 4096; r += 256)
      cntA[(((l << 12) + r) << 4) + c] = sh[r];  // layer2 rows>=1024 stay 0
  }
}

// K2: per-layer (blockIdx = l) padded row scan + inline pad-slot zeroing.
__global__ void __launch_bounds__(1024) scan_kernel(int* __restrict__ cntA,
                                                    int* __restrict__ rowptr,
                                                    int2* __restrict__ edges) {
  int l = blockIdx.x;
  int* rp = rowptr + l * 4104;
  int off = (l == 0) ? 0 : (l == 1) ? EPAD01 : 2 * EPAD01;
  int t = threadIdx.x;  // 1024 threads, 4 rows each
  int tot[4], pad[4];
  int local = 0;
  for (int i = 0; i < 4; ++i) {
    int row = (t << 2) + i;
    const int4* p = (const int4*)(cntA + (((l << 12) + row) << 4));
    int4 a = p[0], b = p[1], cc = p[2], dd = p[3];
    int s = a.x + a.y + a.z + a.w + b.x + b.y + b.z + b.w +
            cc.x + cc.y + cc.z + cc.w + dd.x + dd.y + dd.z + dd.w;
    tot[i] = s;
    pad[i] = (s + 7) & ~7;   // pad row to multiple of 8 (8-edge groups)
    local += pad[i];
  }
  int lane = t & 63, wid = t >> 6;
  int incl = local;
  for (int o = 1; o < 64; o <<= 1) {
    int u = __shfl_up(incl, o, 64);
    if (lane >= o) incl += u;
  }
  __shared__ int wsum[16];
  if (lane == 63) wsum[wid] = incl;
  __syncthreads();
  if (t < 16) {
    int v = wsum[t];
    int iv = v;
    for (int o = 1; o < 16; o <<= 1) {
      int u = __shfl_up(iv, o, 16);
      if (t >= o) iv += u;
    }
    wsum[t] = iv - v;
  }
  __syncthreads();
  int run = wsum[wid] + (incl - local);
  int2 z = make_int2(0, 0);
  for (int i = 0; i < 4; ++i) {
    int row = (t << 2) + i;
    rp[row] = run;
    int* p = cntA + (((l << 12) + row) << 4);
    int acc = run;
    for (int c = 0; c < 16; ++c) { int v = p[c]; p[c] = acc; acc += v; }
    for (int q = run + tot[i]; q < run + pad[i]; ++q) edges[off + q] = z;  // pads
    run += pad[i];
  }
  if (t == 1023) rp[4096] = run;  // rows past n are 0-count; also covers rp[n]
}

// K3: scatter with LDS cursors only. bid = l*16 + c.
__global__ void __launch_bounds__(256) scatter_kernel(
    const int* __restrict__ s0p, const int* __restrict__ d0p, const float* __restrict__ w0p,
    const int* __restrict__ s1p, const int* __restrict__ d1p, const float* __restrict__ w1p,
    const int* __restrict__ s2p, const int* __restrict__ d2p, const float* __restrict__ w2p,
    const int* __restrict__ cntA, int2* __restrict__ edges) {
  int bid = blockIdx.x, l = bid >> 4, c = bid & 15;
  const int* sp = (l == 0) ? s0p : (l == 1) ? s1p : s2p;
  const int* dp = (l == 0) ? d0p : (l == 1) ? d1p : d2p;
  const float* wp = (l == 0) ? w0p : (l == 1) ? w1p : w2p;
  int off = (l == 0) ? 0 : (l == 1) ? EPAD01 : 2 * EPAD01;
  __shared__ int cursor[4096];
  for (int r = threadIdx.x; r < 4096; r += 256)
    cursor[r] = cntA[(((l << 12) + r) << 4) + c];
  __syncthreads();
  int base = c * CHUNK;
  for (int i = 0; i < CHUNK; i += 256) {
    int e = base + i + threadIdx.x;
    int d = dp[e];
    int s = sp[e];
    float wv = wp[e];
    int pos = atomicAdd(&cursor[d], 1);
    edges[off + pos] = make_int2(s, __float_as_int(wv));
  }
}

#define LD4(IDX) (*(const float4*)(hb + ((size_t)(unsigned)(IDX) << 12)))
#define FMA4(A, WB, V) { float _w = __int_as_float(WB); \
  A.x = fmaf(_w, V.x, A.x); A.y = fmaf(_w, V.y, A.y); \
  A.z = fmaf(_w, V.z, A.z); A.w = fmaf(_w, V.w, A.w); }
#define STORE_ROW(RR, O) *(float4*)((char*)outT + (((size_t)(RR) << 12) + ((size_t)col << 2))) = (O)

// SpMM v3: 128-thread block = 2 waves; each wave owns rows r0 (stream A) and
// r0+1 (stream B). Per iteration: 8 scalar edge loads + 8 float4 gathers per
// active stream; A's FMA-wait overlaps B's issue. Epilogue flushes both rows.
__global__ void __launch_bounds__(128) spmm_kernel(const float* __restrict__ hT,
                                                   const int2* __restrict__ edges,
                                                   const int* __restrict__ rowptr,
                                                   const float* __restrict__ bias,
                                                   float* __restrict__ outT) {
  int c = blockIdx.x & 3;
  int rg = blockIdx.x >> 2;
  int w = __builtin_amdgcn_readfirstlane(threadIdx.x >> 6);
  int lane = threadIdx.x & 63;
  int r0 = (rg * 2 + w) * 2;
  int col = (c << 8) + (lane << 2);
  const char* hb = (const char*)(hT + col);

  int eA = rowptr[r0];
  int endA = rowptr[r0 + 1];
  int eB = endA;                 // stream B starts where A's padded range ends
  int endB = rowptr[r0 + 2];

  float4 aA0 = {0.f,0.f,0.f,0.f}, aA1 = {0.f,0.f,0.f,0.f};
  float4 aB0 = {0.f,0.f,0.f,0.f}, aB1 = {0.f,0.f,0.f,0.f};

  while (eA < endA || eB < endB) {
    bool actA = eA < endA, actB = eB < endB;
    iv4 pa0, pa1, pa2, pa3, pb0, pb1, pb2, pb3;
    if (actA) {
      const iv4* ep = (const iv4*)(edges + eA);
      pa0 = ep[0]; pa1 = ep[1]; pa2 = ep[2]; pa3 = ep[3];
    }
    if (actB) {
      const iv4* ep = (const iv4*)(edges + eB);
      pb0 = ep[0]; pb1 = ep[1]; pb2 = ep[2]; pb3 = ep[3];
    }
    if (actA) {
      float4 v0 = LD4(pa0.x), v1 = LD4(pa0.z), v2 = LD4(pa1.x), v3 = LD4(pa1.z);
      float4 v4 = LD4(pa2.x), v5 = LD4(pa2.z), v6 = LD4(pa3.x), v7 = LD4(pa3.z);
      if (actB) {
        // issue B's gathers before consuming A's (overlap A-drain with B-fill)
        float4 u0 = LD4(pb0.x), u1 = LD4(pb0.z), u2 = LD4(pb1.x), u3 = LD4(pb1.z);
        float4 u4 = LD4(pb2.x), u5 = LD4(pb2.z), u6 = LD4(pb3.x), u7 = LD4(pb3.z);
        FMA4(aA0, pa0.y, v0); FMA4(aA1, pa0.w, v1);
        FMA4(aA0, pa1.y, v2); FMA4(aA1, pa1.w, v3);
        FMA4(aA0, pa2.y, v4); FMA4(aA1, pa2.w, v5);
        FMA4(aA0, pa3.y, v6); FMA4(aA1, pa3.w, v7);
        FMA4(aB0, pb0.y, u0); FMA4(aB1, pb0.w, u1);
        FMA4(aB0, pb1.y, u2); FMA4(aB1, pb1.w, u3);
        FMA4(aB0, pb2.y, u4); FMA4(aB1, pb2.w, u5);
        FMA4(aB0, pb3.y, u6); FMA4(aB1, pb3.w, u7);
        eB += 8;
      } else {
        FMA4(aA0, pa0.y, v0); FMA4(aA1, pa0.w, v1);
        FMA4(aA0, pa1.y, v2); FMA4(aA1, pa1.w, v3);
        FMA4(aA0, pa2.y, v4); FMA4(aA1, pa2.w, v5);
        FMA4(aA0, pa3.y, v6); FMA4(aA1, pa3.w, v7);
      }
      eA += 8;
    } else {
      float4 u0 = LD4(pb0.x), u1 = LD4(pb0.z), u2 = LD4(pb1.x), u3 = LD4(pb1.z);
      float4 u4 = LD4(pb2.x), u5 = LD4(pb2.z), u6 = LD4(pb3.x), u7 = LD4(pb3.z);
      FMA4(aB0, pb0.y, u0); FMA4(aB1, pb0.w, u1);
      FMA4(aB0, pb1.y, u2); FMA4(aB1, pb1.w, u3);
      FMA4(aB0, pb2.y, u4); FMA4(aB1, pb2.w, u5);
      FMA4(aB0, pb3.y, u6); FMA4(aB1, pb3.w, u7);
      eB += 8;
    }
  }

  float bA = bias[r0], bB = bias[r0 + 1];
  float4 oA, oB;
  oA.x = fmaxf((aA0.x + aA1.x) + bA, 0.f);
  oA.y = fmaxf((aA0.y + aA1.y) + bA, 0.f);
  oA.z = fmaxf((aA0.z + aA1.z) + bA, 0.f);
  oA.w = fmaxf((aA0.w + aA1.w) + bA, 0.f);
  oB.x = fmaxf((aB0.x + aB1.x) + bB, 0.f);
  oB.y = fmaxf((aB0.y + aB1.y) + bB, 0.f);
  oB.z = fmaxf((aB0.z + aB1.z) + bB, 0.f);
  oB.w = fmaxf((aB0.w + aB1.w) + bB, 0.f);
  STORE_ROW(r0, oA);
  STORE_ROW(r0 + 1, oB);
}

__global__ void transpose_kernel(const float* __restrict__ in, float* __restrict__ out,
                                 int R, int C) {
  __shared__ float tile[32][33];
  int c0 = blockIdx.x << 5, r0 = blockIdx.y << 5;
  int tx = threadIdx.x, ty = threadIdx.y;  // 32 x 8
#pragma unroll
  for (int i = 0; i < 32; i += 8)
    tile[ty + i][tx] = in[(size_t)(r0 + ty + i) * C + (c0 + tx)];
  __syncthreads();
#pragma unroll
  for (int i = 0; i < 32; i += 8)
    out[(size_t)(c0 + ty + i) * R + (r0 + tx)] = tile[tx][ty + i];
}

extern "C" void kernel_launch(void* const* d_in, const int* in_sizes, int n_in,
                              void* d_out, int out_size, void* d_ws, size_t ws_size,
                              hipStream_t stream) {
  const float* x = (const float*)d_in[0];
  const int* src[3]    = {(const int*)d_in[1], (const int*)d_in[5], (const int*)d_in[9]};
  const int* dst[3]    = {(const int*)d_in[2], (const int*)d_in[6], (const int*)d_in[10]};
  const float* w[3]    = {(const float*)d_in[3], (const float*)d_in[7], (const float*)d_in[11]};
  const float* bias[3] = {(const float*)d_in[4], (const float*)d_in[8], (const float*)d_in[12]};
  float* out = (float*)d_out;

  // Workspace (~36.8 MB):
  //   buf0 @ 0          : 16 MB (xT, later h2T)
  //   buf1 @ 16 MB      : 16 MB (h1T, later outT)
  //   rowptr @ 32 MB    : 3*4104 ints
  //   cntA @ +64 KB     : 3*4096*16 ints (per-(row,chunk) counts/offsets)
  //   edges @ 33 MB     : (2*EPAD01+EPAD2) int2, padded CSR
  char* ws = (char*)d_ws;
  float* buf0   = (float*)(ws);
  float* buf1   = (float*)(ws + (16u << 20));
  int*   rowptr = (int*)(ws + (32u << 20));
  int*   cntA   = (int*)(ws + (32u << 20) + 65536u);
  int2*  edges  = (int2*)(ws + (33u << 20));

  fused_tp_count_kernel<<<2048 + 3 * C_CH, 256, 0, stream>>>(
      x, buf0, dst[0], dst[1], dst[2], cntA);
  scan_kernel<<<3, 1024, 0, stream>>>(cntA, rowptr, edges);
  scatter_kernel<<<3 * C_CH, 256, 0, stream>>>(
      src[0], dst[0], w[0], src[1], dst[1], w[1], src[2], dst[2], w[2], cntA, edges);

  // layer 0: buf0 (2048x1024) -> buf1 (4096x1024); 4 rows/block, 4 chunks
  spmm_kernel<<<(4096 / 4) * 4, 128, 0, stream>>>(buf0, edges, rowptr, bias[0], buf1);
  // layer 1: buf1 -> buf0 (4096x1024)
  spmm_kernel<<<(4096 / 4) * 4, 128, 0, stream>>>(buf1, edges + EPAD01, rowptr + 4104, bias[1], buf0);
  // layer 2: buf0 -> buf1 (1024x1024, outT)
  spmm_kernel<<<(1024 / 4) * 4, 128, 0, stream>>>(buf0, edges + 2 * EPAD01, rowptr + 2 * 4104, bias[2], buf1);

  // outT [1024 dst][1024 batch] -> d_out [batch][dst]
  transpose_kernel<<<dim3(1024 / 32, 1024 / 32), dim3(32, 8), 0, stream>>>(buf1, out, 1024, 1024);
}